// Round 7
// baseline (347.279 us; speedup 1.0000x reference)
//
#include <hip/hip_runtime.h>

// All inputs and the output are float32 (established rounds 0-3).
// R6: gemm64s dispatches pinned at ~72us with 3% VALU / 1.4% HBM -> per-dispatch
// cost dominates regardless of in-kernel work. This round collapses the critical
// chain to 3 dispatches: L1 split-K -> mega (L2+prebias+L3+L4+G2+G3 as LDS-resident
// matvecs, one block per (batch-tile=4, rank)) -> fused spline+depth.

__device__ __forceinline__ float leaky(float v) { return v >= 0.f ? v : 0.2f * v; }

// ---------- D0: L1 split-K6 (slice 128): hid1p[z] = (z==0? st_b1:0) + h @ st_w1[slice z]
// grid (32, 1, 6): x -> 2 b-tiles x 16 n-tiles of 32x32; 256 thr, thread 2x2.
__global__ __launch_bounds__(256, 2) void l1_kernel(
    const float* __restrict__ h, const float* __restrict__ W,
    const float* __restrict__ bias, float* __restrict__ outp)
{
    __shared__ __align__(16) float a_lds[128][34];
    __shared__ __align__(16) float w_lds[128][34];
    const int tid = threadIdx.x;
    const int x = blockIdx.x, z = blockIdx.z;
    const int b0 = (x & 1) * 32, n0 = (x >> 1) * 32;
    const int nq = tid & 15, bq = tid >> 4;
    const int k0 = z * 128;
    float a00, a01, a10, a11;
    if (z == 0) {
        float bv0 = bias[n0 + nq * 2], bv1 = bias[n0 + nq * 2 + 1];
        a00 = bv0; a01 = bv1; a10 = bv0; a11 = bv1;
    } else { a00 = a01 = a10 = a11 = 0.f; }
    #pragma unroll
    for (int j = 0; j < 16; ++j) {
        int idx = tid + j * 256;
        int k = idx & 127, c = idx >> 7;          // A: k fastest (coalesced)
        a_lds[k][c] = h[(size_t)(b0 + c) * 768 + k0 + k];
        int n = idx & 31, kk = idx >> 5;          // W: n fastest (coalesced)
        w_lds[kk][n] = W[(size_t)(k0 + kk) * 512 + n0 + n];
    }
    __syncthreads();
    #pragma unroll 32
    for (int kk = 0; kk < 128; ++kk) {
        float2 a = *(const float2*)&a_lds[kk][bq * 2];
        float2 w = *(const float2*)&w_lds[kk][nq * 2];
        a00 += a.x * w.x; a01 += a.x * w.y;
        a10 += a.y * w.x; a11 += a.y * w.y;
    }
    float* ob = outp + (size_t)z * 32768;
    ob[(size_t)(b0 + bq * 2) * 512 + n0 + nq * 2]         = a00;
    ob[(size_t)(b0 + bq * 2) * 512 + n0 + nq * 2 + 1]     = a01;
    ob[(size_t)(b0 + bq * 2 + 1) * 512 + n0 + nq * 2]     = a10;
    ob[(size_t)(b0 + bq * 2 + 1) * 512 + n0 + nq * 2 + 1] = a11;
}

// ---------- D1: mega-middle. Block (bt in [0,16), r in [0,24)), 256 threads.
// Per block: sum hid1 partials + leaky -> L2 matvec -> shared; prebias(r) inline;
// L3 matvec + leaky -> hdn; L4 matvec -> rf; per head (2): G2 matvec + leaky -> hc,
// G3 thin matvec -> Pcat rows. All matvecs: thread = output column, weight loads
// coalesced across lanes, 4 batch rows reuse each weight load.
__global__ __launch_bounds__(256, 2) void mega_kernel(
    const float* __restrict__ hid1p,
    const float* __restrict__ st_w2, const float* __restrict__ st_b2,
    const float* __restrict__ rank_emb,
    const float* __restrict__ rm_w1, const float* __restrict__ rm_b1,
    const float* __restrict__ rm_w2, const float* __restrict__ rm_b2,
    const float* __restrict__ mx_w1, const float* __restrict__ mx_b1,
    const float* __restrict__ mx_w2, const float* __restrict__ mx_b2,
    const float* __restrict__ my_w1, const float* __restrict__ my_b1,
    const float* __restrict__ my_w2, const float* __restrict__ my_b2,
    const float* __restrict__ ax_w1, const float* __restrict__ ax_b1,
    const float* __restrict__ ax_w2, const float* __restrict__ ax_b2,
    const float* __restrict__ ay_w1, const float* __restrict__ ay_b1,
    const float* __restrict__ ay_w2, const float* __restrict__ ay_b2,
    float* __restrict__ Pcat)
{
    __shared__ __align__(16) float hid_s[4][512];
    __shared__ __align__(16) float sh_s[4][256];
    __shared__ __align__(16) float hdn_s[4][256];
    __shared__ __align__(16) float rf_s[4][256];
    __shared__ __align__(16) float hc_s[4][256];
    __shared__ float remb_s[256];
    const int tid = threadIdx.x;
    const int bt = blockIdx.x, r = blockIdx.y;
    const int b0 = bt * 4;

    // stage: hid rows (sum 6 partials + leaky) and rank_emb[r]
    #pragma unroll
    for (int row = 0; row < 4; ++row) {
        for (int j = tid; j < 512; j += 256) {
            size_t off = (size_t)(b0 + row) * 512 + j;
            float v = hid1p[off] + hid1p[32768 + off] + hid1p[2 * 32768 + off]
                    + hid1p[3 * 32768 + off] + hid1p[4 * 32768 + off] + hid1p[5 * 32768 + off];
            hid_s[row][j] = leaky(v);
        }
    }
    remb_s[tid] = rank_emb[r * 256 + tid];
    __syncthreads();

    // L2: shared = hid @ st_w2 + st_b2 (K=512, no activation after)
    {
        float bv = st_b2[tid];
        float a0 = bv, a1 = bv, a2 = bv, a3 = bv;
        const float* wp = st_w2 + tid;
        #pragma unroll 4
        for (int d = 0; d < 512; ++d) {
            float w = wp[(size_t)d * 256];
            a0 += hid_s[0][d] * w; a1 += hid_s[1][d] * w;
            a2 += hid_s[2][d] * w; a3 += hid_s[3][d] * w;
        }
        sh_s[0][tid] = a0; sh_s[1][tid] = a1; sh_s[2][tid] = a2; sh_s[3][tid] = a3;
    }
    __syncthreads();

    // prebias (re_bias[r][tid]) + L3: rfh = shared @ rm_w1[r, :256, :] + re_bias; hdn = leaky
    {
        float rb = rm_b1[r * 256 + tid];
        const float* wb = rm_w1 + ((size_t)r * 512 + 256) * 256 + tid;
        #pragma unroll 4
        for (int d = 0; d < 256; ++d) rb += remb_s[d] * wb[(size_t)d * 256];
        float a0 = rb, a1 = rb, a2 = rb, a3 = rb;
        const float* wa = rm_w1 + (size_t)r * 512 * 256 + tid;
        #pragma unroll 4
        for (int d = 0; d < 256; ++d) {
            float w = wa[(size_t)d * 256];
            a0 += sh_s[0][d] * w; a1 += sh_s[1][d] * w;
            a2 += sh_s[2][d] * w; a3 += sh_s[3][d] * w;
        }
        hdn_s[0][tid] = leaky(a0); hdn_s[1][tid] = leaky(a1);
        hdn_s[2][tid] = leaky(a2); hdn_s[3][tid] = leaky(a3);
    }
    __syncthreads();

    // L4: rf = hdn @ rm_w2[r] + rm_b2[r]  (no activation)
    {
        float bv = rm_b2[r * 256 + tid];
        float a0 = bv, a1 = bv, a2 = bv, a3 = bv;
        const float* wp = rm_w2 + (size_t)r * 65536 + tid;
        #pragma unroll 4
        for (int d = 0; d < 256; ++d) {
            float w = wp[(size_t)d * 256];
            a0 += hdn_s[0][d] * w; a1 += hdn_s[1][d] * w;
            a2 += hdn_s[2][d] * w; a3 += hdn_s[3][d] * w;
        }
        rf_s[0][tid] = a0; rf_s[1][tid] = a1; rf_s[2][tid] = a2; rf_s[3][tid] = a3;
    }
    __syncthreads();

    // two heads per rank: r<16 -> (mx: y=r, my: y=16+r); r>=16 -> rw=r-16 (ax: y=32+rw, ay: y=40+rw)
    for (int hh = 0; hh < 2; ++hh) {
        const float *W1, *B1, *W2, *B2; int y;
        if (r < 16) {
            if (hh == 0) { y = r;      W1 = mx_w1 + (size_t)r * 65536;  B1 = mx_b1 + r * 256;  W2 = mx_w2 + (size_t)r * 6144;  B2 = mx_b2 + r * 24; }
            else         { y = 16 + r; W1 = my_w1 + (size_t)r * 65536;  B1 = my_b1 + r * 256;  W2 = my_w2 + (size_t)r * 6144;  B2 = my_b2 + r * 24; }
        } else {
            int rw = r - 16;
            if (hh == 0) { y = 32 + rw; W1 = ax_w1 + (size_t)rw * 65536; B1 = ax_b1 + rw * 256; W2 = ax_w2 + (size_t)rw * 6144; B2 = ax_b2 + rw * 24; }
            else         { y = 40 + rw; W1 = ay_w1 + (size_t)rw * 65536; B1 = ay_b1 + rw * 256; W2 = ay_w2 + (size_t)rw * 6144; B2 = ay_b2 + rw * 24; }
        }
        // G2: hc = leaky(rf @ W1 + B1)
        {
            float bv = B1[tid];
            float a0 = bv, a1 = bv, a2 = bv, a3 = bv;
            const float* wp = W1 + tid;
            #pragma unroll 4
            for (int d = 0; d < 256; ++d) {
                float w = wp[(size_t)d * 256];
                a0 += rf_s[0][d] * w; a1 += rf_s[1][d] * w;
                a2 += rf_s[2][d] * w; a3 += rf_s[3][d] * w;
            }
            hc_s[0][tid] = leaky(a0); hc_s[1][tid] = leaky(a1);
            hc_s[2][tid] = leaky(a2); hc_s[3][tid] = leaky(a3);
        }
        __syncthreads();
        // G3: Pcat rows (4 rows x 24 cols = 96 outputs)
        if (tid < 96) {
            int row = tid / 24, j = tid - row * 24;
            float acc = B2[j];
            #pragma unroll 4
            for (int c = 0; c < 256; ++c) acc += hc_s[row][c] * W2[(size_t)c * 24 + j];
            Pcat[(size_t)(b0 + row) * 1152 + y * 24 + j] = acc;
        }
        __syncthreads();
    }
}

// ---------- D2: fused spline + depth (unchanged geometry; single Pcat buffer).
// Pcat rows: [Px_m 0..15, Py_m 16..31, Px_a 32..39, Py_a 40..47]
__global__ __launch_bounds__(256, 2) void depth_fused_kernel(
    const float* __restrict__ Pcat,
    const float* __restrict__ mult_w, const float* __restrict__ addx_w,
    const float* __restrict__ addy_w, const float* __restrict__ gbias,
    float* __restrict__ out)
{
    __shared__ float cp[48][25];
    __shared__ float sw[33];
    __shared__ __align__(16) float u_s[16][132];
    __shared__ __align__(16) float v_s[16][132];
    __shared__ float dx_s[128], dy_s[128];
    const int tid = threadIdx.x;
    const int b = blockIdx.z, h0 = blockIdx.y * 128, w0 = blockIdx.x * 128;
    for (int idx = tid; idx < 1152; idx += 256)
        cp[idx / 24][idx % 24] = Pcat[(size_t)b * 1152 + idx];
    if (tid == 0) {
        float e[16], m, s;
        m = -1e30f; for (int i = 0; i < 16; ++i) m = fmaxf(m, mult_w[i]);
        s = 0.f;    for (int i = 0; i < 16; ++i) { e[i] = __expf(mult_w[i] - m); s += e[i]; }
        for (int i = 0; i < 16; ++i) sw[i] = e[i] / s;
        m = -1e30f; for (int i = 0; i < 8; ++i) m = fmaxf(m, addx_w[i]);
        s = 0.f;    for (int i = 0; i < 8; ++i) { e[i] = __expf(addx_w[i] - m); s += e[i]; }
        for (int i = 0; i < 8; ++i) sw[16 + i] = e[i] / s;
        m = -1e30f; for (int i = 0; i < 8; ++i) m = fmaxf(m, addy_w[i]);
        s = 0.f;    for (int i = 0; i < 8; ++i) { e[i] = __expf(addy_w[i] - m); s += e[i]; }
        for (int i = 0; i < 8; ++i) sw[24 + i] = e[i] / s;
        sw[32] = gbias[0];
    }
    __syncthreads();
    {   // spline: tid<128 -> w positions; tid>=128 -> h positions
        const int local = tid & 127;
        const int gpos = (tid < 128 ? w0 : h0) + local;
        const float eps = 0.001f;
        float t = eps + (float)gpos * ((1.f - 2.f * eps) / 511.f);
        float ts = t * 23.f;
        int seg = (int)ts; if (seg > 22) seg = 22;
        float tau = ts - (float)seg;
        tau = fminf(fmaxf(tau, 0.f), 0.9999f);
        float t2 = tau * tau, t3 = t2 * tau;
        float h00 = 2.f * t3 - 3.f * t2 + 1.f;
        float h10 = t3 - 2.f * t2 + tau;
        float h01 = -2.f * t3 + 3.f * t2;
        float h11 = t3 - t2;
        int sm1 = seg > 0 ? seg - 1 : 0;
        int s1 = seg + 1;
        int sp2 = s1 < 23 ? s1 + 1 : 23;
        const float msc = 0.5f / 23.f;
        auto spl = [&](int row) -> float {
            float pk = cp[row][seg], pk1 = cp[row][s1];
            float mk  = msc * (pk1 - cp[row][sm1]);
            float mk1 = msc * (cp[row][sp2] - pk);
            return h00 * pk + h10 * mk + h01 * pk1 + h11 * mk1;
        };
        if (tid < 128) {
            #pragma unroll
            for (int r = 0; r < 16; ++r) u_s[r][local] = sw[r] * spl(r);
            float dx = sw[32];
            #pragma unroll
            for (int r = 0; r < 8; ++r) dx += sw[16 + r] * spl(32 + r);
            dx_s[local] = dx;
        } else {
            #pragma unroll
            for (int r = 0; r < 16; ++r) v_s[r][local] = spl(16 + r);
            float dy = 0.f;
            #pragma unroll
            for (int r = 0; r < 8; ++r) dy += sw[24 + r] * spl(40 + r);
            dy_s[local] = dy;
        }
    }
    __syncthreads();
    const int tw = tid & 15, th = tid >> 4;
    float acc[8][8];
    #pragma unroll
    for (int i = 0; i < 8; ++i)
        #pragma unroll
        for (int j = 0; j < 8; ++j) acc[i][j] = 0.f;
    #pragma unroll
    for (int r = 0; r < 16; ++r) {
        float4 va0 = *(const float4*)&v_s[r][th * 8];
        float4 va1 = *(const float4*)&v_s[r][th * 8 + 4];
        float4 ub0 = *(const float4*)&u_s[r][tw * 8];
        float4 ub1 = *(const float4*)&u_s[r][tw * 8 + 4];
        float va[8] = {va0.x, va0.y, va0.z, va0.w, va1.x, va1.y, va1.z, va1.w};
        float ub[8] = {ub0.x, ub0.y, ub0.z, ub0.w, ub1.x, ub1.y, ub1.z, ub1.w};
        #pragma unroll
        for (int i = 0; i < 8; ++i)
            #pragma unroll
            for (int j = 0; j < 8; ++j)
                acc[i][j] += va[i] * ub[j];
    }
    #pragma unroll
    for (int i = 0; i < 8; ++i) {
        float dyh = dy_s[th * 8 + i];
        float* op = out + (size_t)b * 262144 + (size_t)(h0 + th * 8 + i) * 512 + w0 + tw * 8;
        float4 o0, o1;
        o0.x = acc[i][0] + dx_s[tw * 8 + 0] + dyh;
        o0.y = acc[i][1] + dx_s[tw * 8 + 1] + dyh;
        o0.z = acc[i][2] + dx_s[tw * 8 + 2] + dyh;
        o0.w = acc[i][3] + dx_s[tw * 8 + 3] + dyh;
        o1.x = acc[i][4] + dx_s[tw * 8 + 4] + dyh;
        o1.y = acc[i][5] + dx_s[tw * 8 + 5] + dyh;
        o1.z = acc[i][6] + dx_s[tw * 8 + 6] + dyh;
        o1.w = acc[i][7] + dx_s[tw * 8 + 7] + dyh;
        *(float4*)op = o0;
        *(float4*)(op + 4) = o1;
    }
}

// ---------- host ----------
extern "C" void kernel_launch(void* const* d_in, const int* in_sizes, int n_in,
                              void* d_out, int out_size, void* d_ws, size_t ws_size,
                              hipStream_t stream) {
    const float* in_h     = (const float*)d_in[0];
    const float* rank_emb = (const float*)d_in[1];
    const float* st_w1    = (const float*)d_in[2];
    const float* st_b1    = (const float*)d_in[3];
    const float* st_w2    = (const float*)d_in[4];
    const float* st_b2    = (const float*)d_in[5];
    const float* rm_w1    = (const float*)d_in[6];
    const float* rm_b1    = (const float*)d_in[7];
    const float* rm_w2    = (const float*)d_in[8];
    const float* rm_b2    = (const float*)d_in[9];
    const float* mx_w1    = (const float*)d_in[10];
    const float* mx_b1    = (const float*)d_in[11];
    const float* mx_w2    = (const float*)d_in[12];
    const float* mx_b2    = (const float*)d_in[13];
    const float* my_w1    = (const float*)d_in[14];
    const float* my_b1    = (const float*)d_in[15];
    const float* my_w2    = (const float*)d_in[16];
    const float* my_b2    = (const float*)d_in[17];
    const float* ax_w1    = (const float*)d_in[18];
    const float* ax_b1    = (const float*)d_in[19];
    const float* ax_w2    = (const float*)d_in[20];
    const float* ax_b2    = (const float*)d_in[21];
    const float* ay_w1    = (const float*)d_in[22];
    const float* ay_b1    = (const float*)d_in[23];
    const float* ay_w2    = (const float*)d_in[24];
    const float* ay_b2    = (const float*)d_in[25];
    const float* mult_w   = (const float*)d_in[26];
    const float* addx_w   = (const float*)d_in[27];
    const float* addy_w   = (const float*)d_in[28];
    const float* gbias    = (const float*)d_in[29];
    (void)in_sizes; (void)n_in; (void)out_size; (void)ws_size;

    float* ws = (float*)d_ws;
    float* hid1p = ws;               // 6 x (64x512) = 196608 floats
    float* Pcat  = ws + 196608;      // 64x48x24     = 73728 floats

    // D0: L1 split-K6 -> hid1p[6]
    l1_kernel<<<dim3(32, 1, 6), 256, 0, stream>>>(in_h, st_w1, st_b1, hid1p);

    // D1: mega-middle -> Pcat
    mega_kernel<<<dim3(16, 24), 256, 0, stream>>>(
        hid1p, st_w2, st_b2, rank_emb,
        rm_w1, rm_b1, rm_w2, rm_b2,
        mx_w1, mx_b1, mx_w2, mx_b2,
        my_w1, my_b1, my_w2, my_b2,
        ax_w1, ax_b1, ax_w2, ax_b2,
        ay_w1, ay_b1, ay_w2, ay_b2,
        Pcat);

    // D2: fused spline + depth
    depth_fused_kernel<<<dim3(4, 4, 64), 256, 0, stream>>>(
        Pcat, mult_w, addx_w, addy_w, gbias, (float*)d_out);
}

// Round 8
// 239.920 us; speedup vs baseline: 1.4475x; 1.4475x over previous
//
#include <hip/hip_runtime.h>

// All inputs and the output are float32 (established rounds 0-3).
// R7: mega_kernel = 240us, FETCH 130MB vs ~33MB unique weights -> per-rank weights
// re-streamed by 16 blocks scattered over 8 non-coherent XCD L2s. This round:
// 8 rows/block (8 blocks/rank), 1D grid with r = blk%24 so all blocks of a rank
// land on one XCD (24 = 0 mod 8 -> blk = r mod 8), float4-chunked inner loops,
// two heads computed in parallel by the two 256-thread halves.

__device__ __forceinline__ float leaky(float v) { return v >= 0.f ? v : 0.2f * v; }

// ---------- D0: L1 split-K6 (slice 128): hid1p[z] = (z==0? st_b1:0) + h @ st_w1[slice z]
__global__ __launch_bounds__(256, 2) void l1_kernel(
    const float* __restrict__ h, const float* __restrict__ W,
    const float* __restrict__ bias, float* __restrict__ outp)
{
    __shared__ __align__(16) float a_lds[128][34];
    __shared__ __align__(16) float w_lds[128][34];
    const int tid = threadIdx.x;
    const int x = blockIdx.x, z = blockIdx.z;
    const int b0 = (x & 1) * 32, n0 = (x >> 1) * 32;
    const int nq = tid & 15, bq = tid >> 4;
    const int k0 = z * 128;
    float a00, a01, a10, a11;
    if (z == 0) {
        float bv0 = bias[n0 + nq * 2], bv1 = bias[n0 + nq * 2 + 1];
        a00 = bv0; a01 = bv1; a10 = bv0; a11 = bv1;
    } else { a00 = a01 = a10 = a11 = 0.f; }
    #pragma unroll
    for (int j = 0; j < 16; ++j) {
        int idx = tid + j * 256;
        int k = idx & 127, c = idx >> 7;
        a_lds[k][c] = h[(size_t)(b0 + c) * 768 + k0 + k];
        int n = idx & 31, kk = idx >> 5;
        w_lds[kk][n] = W[(size_t)(k0 + kk) * 512 + n0 + n];
    }
    __syncthreads();
    #pragma unroll 32
    for (int kk = 0; kk < 128; ++kk) {
        float2 a = *(const float2*)&a_lds[kk][bq * 2];
        float2 w = *(const float2*)&w_lds[kk][nq * 2];
        a00 += a.x * w.x; a01 += a.x * w.y;
        a10 += a.y * w.x; a11 += a.y * w.y;
    }
    float* ob = outp + (size_t)z * 32768;
    ob[(size_t)(b0 + bq * 2) * 512 + n0 + nq * 2]         = a00;
    ob[(size_t)(b0 + bq * 2) * 512 + n0 + nq * 2 + 1]     = a01;
    ob[(size_t)(b0 + bq * 2 + 1) * 512 + n0 + nq * 2]     = a10;
    ob[(size_t)(b0 + bq * 2 + 1) * 512 + n0 + nq * 2 + 1] = a11;
}

// ---------- D1: mega-middle. 192 blocks x 512 thr. blk -> (r = blk%24, bt = blk/24).
// 8 batch rows per block; col = tid&255, rh = tid>>8 handles rows rh*4..rh*4+3
// (and head rh in G2/G3). All matvec weight loads coalesced; LDS activations.
__global__ __launch_bounds__(512, 1) void mega_kernel(
    const float* __restrict__ hid1p,
    const float* __restrict__ st_w2, const float* __restrict__ st_b2,
    const float* __restrict__ rank_emb,
    const float* __restrict__ rm_w1, const float* __restrict__ rm_b1,
    const float* __restrict__ rm_w2, const float* __restrict__ rm_b2,
    const float* __restrict__ mx_w1, const float* __restrict__ mx_b1,
    const float* __restrict__ mx_w2, const float* __restrict__ mx_b2,
    const float* __restrict__ my_w1, const float* __restrict__ my_b1,
    const float* __restrict__ my_w2, const float* __restrict__ my_b2,
    const float* __restrict__ ax_w1, const float* __restrict__ ax_b1,
    const float* __restrict__ ax_w2, const float* __restrict__ ax_b2,
    const float* __restrict__ ay_w1, const float* __restrict__ ay_b1,
    const float* __restrict__ ay_w2, const float* __restrict__ ay_b2,
    float* __restrict__ Pcat)
{
    __shared__ __align__(16) float hid_s[8][512];
    __shared__ __align__(16) float sh_s[8][256];
    __shared__ __align__(16) float hdn_s[8][256];
    __shared__ __align__(16) float rf_s[8][256];
    __shared__ __align__(16) float hc_s[2][8][256];
    __shared__ float re_s[256];
    __shared__ float remb_s[256];
    const int tid = threadIdx.x;
    const int blk = blockIdx.x;
    const int r = blk % 24;          // blk = r (mod 8): all 8 blocks of a rank on one XCD
    const int bt = blk / 24;         // 0..7
    const int b0 = bt * 8;
    const int col = tid & 255, rh = tid >> 8;
    const int r0 = rh * 4;

    // stage: 8 hid rows (sum 6 L1 partials + leaky), float4-vectorized
    {
        const float4* hp = (const float4*)hid1p;   // partial p at offset p*8192 (float4)
        #pragma unroll
        for (int i = 0; i < 2; ++i) {
            int idx = tid + i * 512;               // 0..1023
            int row = idx >> 7, j4 = idx & 127;
            size_t off = (size_t)(b0 + row) * 128 + j4;
            float4 v0 = hp[off],            v1 = hp[8192 + off],  v2 = hp[16384 + off];
            float4 v3 = hp[24576 + off],    v4 = hp[32768 + off], v5 = hp[40960 + off];
            float4 s;
            s.x = leaky(v0.x + v1.x + v2.x + v3.x + v4.x + v5.x);
            s.y = leaky(v0.y + v1.y + v2.y + v3.y + v4.y + v5.y);
            s.z = leaky(v0.z + v1.z + v2.z + v3.z + v4.z + v5.z);
            s.w = leaky(v0.w + v1.w + v2.w + v3.w + v4.w + v5.w);
            ((float4*)&hid_s[row][0])[j4] = s;
        }
    }
    if (tid < 256) remb_s[tid] = rank_emb[r * 256 + tid];
    __syncthreads();

    // L2: sh = hid @ st_w2 + st_b2 (K=512, no activation)
    {
        float bv = st_b2[col];
        float a0 = bv, a1 = bv, a2 = bv, a3 = bv;
        const float* wp = st_w2 + col;
        #pragma unroll 4
        for (int d = 0; d < 512; d += 4) {
            float w0 = wp[(size_t)(d + 0) * 256], w1 = wp[(size_t)(d + 1) * 256];
            float w2 = wp[(size_t)(d + 2) * 256], w3 = wp[(size_t)(d + 3) * 256];
            float4 s0 = *(const float4*)&hid_s[r0 + 0][d];
            float4 s1 = *(const float4*)&hid_s[r0 + 1][d];
            float4 s2 = *(const float4*)&hid_s[r0 + 2][d];
            float4 s3 = *(const float4*)&hid_s[r0 + 3][d];
            a0 += s0.x * w0 + s0.y * w1 + s0.z * w2 + s0.w * w3;
            a1 += s1.x * w0 + s1.y * w1 + s1.z * w2 + s1.w * w3;
            a2 += s2.x * w0 + s2.y * w1 + s2.z * w2 + s2.w * w3;
            a3 += s3.x * w0 + s3.y * w1 + s3.z * w2 + s3.w * w3;
        }
        sh_s[r0 + 0][col] = a0; sh_s[r0 + 1][col] = a1;
        sh_s[r0 + 2][col] = a2; sh_s[r0 + 3][col] = a3;
    }
    __syncthreads();

    // prebias: re_s = rm_b1[r] + rank_emb[r] @ rm_w1[r, 256:, :]
    if (tid < 256) {
        float rb = rm_b1[r * 256 + col];
        const float* wb = rm_w1 + ((size_t)r * 512 + 256) * 256 + col;
        #pragma unroll 4
        for (int d = 0; d < 256; d += 4) {
            float w0 = wb[(size_t)(d + 0) * 256], w1 = wb[(size_t)(d + 1) * 256];
            float w2 = wb[(size_t)(d + 2) * 256], w3 = wb[(size_t)(d + 3) * 256];
            float4 e = *(const float4*)&remb_s[d];
            rb += e.x * w0 + e.y * w1 + e.z * w2 + e.w * w3;
        }
        re_s[col] = rb;
    }
    __syncthreads();

    // L3: hdn = leaky(sh @ rm_w1[r, :256, :] + re_s)
    {
        float bv = re_s[col];
        float a0 = bv, a1 = bv, a2 = bv, a3 = bv;
        const float* wp = rm_w1 + (size_t)r * 512 * 256 + col;
        #pragma unroll 4
        for (int d = 0; d < 256; d += 4) {
            float w0 = wp[(size_t)(d + 0) * 256], w1 = wp[(size_t)(d + 1) * 256];
            float w2 = wp[(size_t)(d + 2) * 256], w3 = wp[(size_t)(d + 3) * 256];
            float4 s0 = *(const float4*)&sh_s[r0 + 0][d];
            float4 s1 = *(const float4*)&sh_s[r0 + 1][d];
            float4 s2 = *(const float4*)&sh_s[r0 + 2][d];
            float4 s3 = *(const float4*)&sh_s[r0 + 3][d];
            a0 += s0.x * w0 + s0.y * w1 + s0.z * w2 + s0.w * w3;
            a1 += s1.x * w0 + s1.y * w1 + s1.z * w2 + s1.w * w3;
            a2 += s2.x * w0 + s2.y * w1 + s2.z * w2 + s2.w * w3;
            a3 += s3.x * w0 + s3.y * w1 + s3.z * w2 + s3.w * w3;
        }
        hdn_s[r0 + 0][col] = leaky(a0); hdn_s[r0 + 1][col] = leaky(a1);
        hdn_s[r0 + 2][col] = leaky(a2); hdn_s[r0 + 3][col] = leaky(a3);
    }
    __syncthreads();

    // L4: rf = hdn @ rm_w2[r] + rm_b2[r] (no activation)
    {
        float bv = rm_b2[r * 256 + col];
        float a0 = bv, a1 = bv, a2 = bv, a3 = bv;
        const float* wp = rm_w2 + (size_t)r * 65536 + col;
        #pragma unroll 4
        for (int d = 0; d < 256; d += 4) {
            float w0 = wp[(size_t)(d + 0) * 256], w1 = wp[(size_t)(d + 1) * 256];
            float w2 = wp[(size_t)(d + 2) * 256], w3 = wp[(size_t)(d + 3) * 256];
            float4 s0 = *(const float4*)&hdn_s[r0 + 0][d];
            float4 s1 = *(const float4*)&hdn_s[r0 + 1][d];
            float4 s2 = *(const float4*)&hdn_s[r0 + 2][d];
            float4 s3 = *(const float4*)&hdn_s[r0 + 3][d];
            a0 += s0.x * w0 + s0.y * w1 + s0.z * w2 + s0.w * w3;
            a1 += s1.x * w0 + s1.y * w1 + s1.z * w2 + s1.w * w3;
            a2 += s2.x * w0 + s2.y * w1 + s2.z * w2 + s2.w * w3;
            a3 += s3.x * w0 + s3.y * w1 + s3.z * w2 + s3.w * w3;
        }
        rf_s[r0 + 0][col] = a0; rf_s[r0 + 1][col] = a1;
        rf_s[r0 + 2][col] = a2; rf_s[r0 + 3][col] = a3;
    }
    __syncthreads();

    // head selection: head = rh.  r<16: head0=mx(y=r), head1=my(y=16+r);
    // r>=16: rw=r-16: head0=ax(y=32+rw), head1=ay(y=40+rw)
    const float *W1, *B1, *W2, *B2; int y;
    if (r < 16) {
        if (rh == 0) { y = r;      W1 = mx_w1 + (size_t)r * 65536;  B1 = mx_b1 + r * 256;  W2 = mx_w2 + (size_t)r * 6144;  B2 = mx_b2 + r * 24; }
        else         { y = 16 + r; W1 = my_w1 + (size_t)r * 65536;  B1 = my_b1 + r * 256;  W2 = my_w2 + (size_t)r * 6144;  B2 = my_b2 + r * 24; }
    } else {
        int rw = r - 16;
        if (rh == 0) { y = 32 + rw; W1 = ax_w1 + (size_t)rw * 65536; B1 = ax_b1 + rw * 256; W2 = ax_w2 + (size_t)rw * 6144; B2 = ax_b2 + rw * 24; }
        else         { y = 40 + rw; W1 = ay_w1 + (size_t)rw * 65536; B1 = ay_b1 + rw * 256; W2 = ay_w2 + (size_t)rw * 6144; B2 = ay_b2 + rw * 24; }
    }

    // G2 (head rh): hc[rh] = leaky(rf @ W1 + B1), all 8 rows per thread
    {
        float bv = B1[col];
        float acc[8];
        #pragma unroll
        for (int i = 0; i < 8; ++i) acc[i] = bv;
        const float* wp = W1 + col;
        #pragma unroll 2
        for (int d = 0; d < 256; d += 4) {
            float w0 = wp[(size_t)(d + 0) * 256], w1 = wp[(size_t)(d + 1) * 256];
            float w2 = wp[(size_t)(d + 2) * 256], w3 = wp[(size_t)(d + 3) * 256];
            #pragma unroll
            for (int i = 0; i < 8; ++i) {
                float4 s = *(const float4*)&rf_s[i][d];
                acc[i] += s.x * w0 + s.y * w1 + s.z * w2 + s.w * w3;
            }
        }
        #pragma unroll
        for (int i = 0; i < 8; ++i) hc_s[rh][i][col] = leaky(acc[i]);
    }
    __syncthreads();

    // G3 (head rh): Pcat rows for y; 8 rows x 24 cols = 192 active threads per half
    if (col < 192) {
        int row = col / 24, cj = col - row * 24;
        float acc = B2[cj];
        const float* wp = W2 + cj;
        #pragma unroll 4
        for (int d = 0; d < 256; d += 4) {
            float w0 = wp[(size_t)(d + 0) * 24], w1 = wp[(size_t)(d + 1) * 24];
            float w2 = wp[(size_t)(d + 2) * 24], w3 = wp[(size_t)(d + 3) * 24];
            float4 s = *(const float4*)&hc_s[rh][row][d];
            acc += s.x * w0 + s.y * w1 + s.z * w2 + s.w * w3;
        }
        Pcat[(size_t)(b0 + row) * 1152 + y * 24 + cj] = acc;
    }
}

// ---------- D2: fused spline + depth (unchanged).
// Pcat rows: [Px_m 0..15, Py_m 16..31, Px_a 32..39, Py_a 40..47]
__global__ __launch_bounds__(256, 2) void depth_fused_kernel(
    const float* __restrict__ Pcat,
    const float* __restrict__ mult_w, const float* __restrict__ addx_w,
    const float* __restrict__ addy_w, const float* __restrict__ gbias,
    float* __restrict__ out)
{
    __shared__ float cp[48][25];
    __shared__ float sw[33];
    __shared__ __align__(16) float u_s[16][132];
    __shared__ __align__(16) float v_s[16][132];
    __shared__ float dx_s[128], dy_s[128];
    const int tid = threadIdx.x;
    const int b = blockIdx.z, h0 = blockIdx.y * 128, w0 = blockIdx.x * 128;
    for (int idx = tid; idx < 1152; idx += 256)
        cp[idx / 24][idx % 24] = Pcat[(size_t)b * 1152 + idx];
    if (tid == 0) {
        float e[16], m, s;
        m = -1e30f; for (int i = 0; i < 16; ++i) m = fmaxf(m, mult_w[i]);
        s = 0.f;    for (int i = 0; i < 16; ++i) { e[i] = __expf(mult_w[i] - m); s += e[i]; }
        for (int i = 0; i < 16; ++i) sw[i] = e[i] / s;
        m = -1e30f; for (int i = 0; i < 8; ++i) m = fmaxf(m, addx_w[i]);
        s = 0.f;    for (int i = 0; i < 8; ++i) { e[i] = __expf(addx_w[i] - m); s += e[i]; }
        for (int i = 0; i < 8; ++i) sw[16 + i] = e[i] / s;
        m = -1e30f; for (int i = 0; i < 8; ++i) m = fmaxf(m, addy_w[i]);
        s = 0.f;    for (int i = 0; i < 8; ++i) { e[i] = __expf(addy_w[i] - m); s += e[i]; }
        for (int i = 0; i < 8; ++i) sw[24 + i] = e[i] / s;
        sw[32] = gbias[0];
    }
    __syncthreads();
    {
        const int local = tid & 127;
        const int gpos = (tid < 128 ? w0 : h0) + local;
        const float eps = 0.001f;
        float t = eps + (float)gpos * ((1.f - 2.f * eps) / 511.f);
        float ts = t * 23.f;
        int seg = (int)ts; if (seg > 22) seg = 22;
        float tau = ts - (float)seg;
        tau = fminf(fmaxf(tau, 0.f), 0.9999f);
        float t2 = tau * tau, t3 = t2 * tau;
        float h00 = 2.f * t3 - 3.f * t2 + 1.f;
        float h10 = t3 - 2.f * t2 + tau;
        float h01 = -2.f * t3 + 3.f * t2;
        float h11 = t3 - t2;
        int sm1 = seg > 0 ? seg - 1 : 0;
        int s1 = seg + 1;
        int sp2 = s1 < 23 ? s1 + 1 : 23;
        const float msc = 0.5f / 23.f;
        auto spl = [&](int row) -> float {
            float pk = cp[row][seg], pk1 = cp[row][s1];
            float mk  = msc * (pk1 - cp[row][sm1]);
            float mk1 = msc * (cp[row][sp2] - pk);
            return h00 * pk + h10 * mk + h01 * pk1 + h11 * mk1;
        };
        if (tid < 128) {
            #pragma unroll
            for (int r = 0; r < 16; ++r) u_s[r][local] = sw[r] * spl(r);
            float dx = sw[32];
            #pragma unroll
            for (int r = 0; r < 8; ++r) dx += sw[16 + r] * spl(32 + r);
            dx_s[local] = dx;
        } else {
            #pragma unroll
            for (int r = 0; r < 16; ++r) v_s[r][local] = spl(16 + r);
            float dy = 0.f;
            #pragma unroll
            for (int r = 0; r < 8; ++r) dy += sw[24 + r] * spl(40 + r);
            dy_s[local] = dy;
        }
    }
    __syncthreads();
    const int tw = tid & 15, th = tid >> 4;
    float acc[8][8];
    #pragma unroll
    for (int i = 0; i < 8; ++i)
        #pragma unroll
        for (int j = 0; j < 8; ++j) acc[i][j] = 0.f;
    #pragma unroll
    for (int r = 0; r < 16; ++r) {
        float4 va0 = *(const float4*)&v_s[r][th * 8];
        float4 va1 = *(const float4*)&v_s[r][th * 8 + 4];
        float4 ub0 = *(const float4*)&u_s[r][tw * 8];
        float4 ub1 = *(const float4*)&u_s[r][tw * 8 + 4];
        float va[8] = {va0.x, va0.y, va0.z, va0.w, va1.x, va1.y, va1.z, va1.w};
        float ub[8] = {ub0.x, ub0.y, ub0.z, ub0.w, ub1.x, ub1.y, ub1.z, ub1.w};
        #pragma unroll
        for (int i = 0; i < 8; ++i)
            #pragma unroll
            for (int j = 0; j < 8; ++j)
                acc[i][j] += va[i] * ub[j];
    }
    #pragma unroll
    for (int i = 0; i < 8; ++i) {
        float dyh = dy_s[th * 8 + i];
        float* op = out + (size_t)b * 262144 + (size_t)(h0 + th * 8 + i) * 512 + w0 + tw * 8;
        float4 o0, o1;
        o0.x = acc[i][0] + dx_s[tw * 8 + 0] + dyh;
        o0.y = acc[i][1] + dx_s[tw * 8 + 1] + dyh;
        o0.z = acc[i][2] + dx_s[tw * 8 + 2] + dyh;
        o0.w = acc[i][3] + dx_s[tw * 8 + 3] + dyh;
        o1.x = acc[i][4] + dx_s[tw * 8 + 4] + dyh;
        o1.y = acc[i][5] + dx_s[tw * 8 + 5] + dyh;
        o1.z = acc[i][6] + dx_s[tw * 8 + 6] + dyh;
        o1.w = acc[i][7] + dx_s[tw * 8 + 7] + dyh;
        *(float4*)op = o0;
        *(float4*)(op + 4) = o1;
    }
}

// ---------- host ----------
extern "C" void kernel_launch(void* const* d_in, const int* in_sizes, int n_in,
                              void* d_out, int out_size, void* d_ws, size_t ws_size,
                              hipStream_t stream) {
    const float* in_h     = (const float*)d_in[0];
    const float* rank_emb = (const float*)d_in[1];
    const float* st_w1    = (const float*)d_in[2];
    const float* st_b1    = (const float*)d_in[3];
    const float* st_w2    = (const float*)d_in[4];
    const float* st_b2    = (const float*)d_in[5];
    const float* rm_w1    = (const float*)d_in[6];
    const float* rm_b1    = (const float*)d_in[7];
    const float* rm_w2    = (const float*)d_in[8];
    const float* rm_b2    = (const float*)d_in[9];
    const float* mx_w1    = (const float*)d_in[10];
    const float* mx_b1    = (const float*)d_in[11];
    const float* mx_w2    = (const float*)d_in[12];
    const float* mx_b2    = (const float*)d_in[13];
    const float* my_w1    = (const float*)d_in[14];
    const float* my_b1    = (const float*)d_in[15];
    const float* my_w2    = (const float*)d_in[16];
    const float* my_b2    = (const float*)d_in[17];
    const float* ax_w1    = (const float*)d_in[18];
    const float* ax_b1    = (const float*)d_in[19];
    const float* ax_w2    = (const float*)d_in[20];
    const float* ax_b2    = (const float*)d_in[21];
    const float* ay_w1    = (const float*)d_in[22];
    const float* ay_b1    = (const float*)d_in[23];
    const float* ay_w2    = (const float*)d_in[24];
    const float* ay_b2    = (const float*)d_in[25];
    const float* mult_w   = (const float*)d_in[26];
    const float* addx_w   = (const float*)d_in[27];
    const float* addy_w   = (const float*)d_in[28];
    const float* gbias    = (const float*)d_in[29];
    (void)in_sizes; (void)n_in; (void)out_size; (void)ws_size;

    float* ws = (float*)d_ws;
    float* hid1p = ws;               // 6 x (64x512) = 196608 floats
    float* Pcat  = ws + 196608;      // 64x48x24     = 73728 floats

    // D0: L1 split-K6 -> hid1p[6]
    l1_kernel<<<dim3(32, 1, 6), 256, 0, stream>>>(in_h, st_w1, st_b1, hid1p);

    // D1: mega-middle -> Pcat (1D grid, XCD-clustered by rank)
    mega_kernel<<<192, 512, 0, stream>>>(
        hid1p, st_w2, st_b2, rank_emb,
        rm_w1, rm_b1, rm_w2, rm_b2,
        mx_w1, mx_b1, mx_w2, mx_b2,
        my_w1, my_b1, my_w2, my_b2,
        ax_w1, ax_b1, ax_w2, ax_b2,
        ay_w1, ay_b1, ay_w2, ay_b2,
        Pcat);

    // D2: fused spline + depth
    depth_fused_kernel<<<dim3(4, 4, 64), 256, 0, stream>>>(
        Pcat, mult_w, addx_w, addy_w, gbias, (float*)d_out);
}